// Round 1
// baseline (525.398 us; speedup 1.0000x reference)
//
#include <hip/hip_runtime.h>
#include <hip/hip_bf16.h>

#define EMB 16

// ---------------------------------------------------------------------------
// Kernel 1: per-node linear transform  Y[n] = X[n] @ W.T (+ b)
// One thread per node. W (16x16) and b staged in LDS.
// ---------------------------------------------------------------------------
__global__ __launch_bounds__(256) void node_transform_kernel(
    const float* __restrict__ X, const float* __restrict__ W,
    const float* __restrict__ b, float* __restrict__ Y, int N) {
    __shared__ float sW[EMB * EMB];
    __shared__ float sb[EMB];
    if (threadIdx.x < EMB * EMB) sW[threadIdx.x] = W[threadIdx.x];
    if (threadIdx.x < EMB) sb[threadIdx.x] = (b != nullptr) ? b[threadIdx.x] : 0.0f;
    __syncthreads();

    int n = blockIdx.x * blockDim.x + threadIdx.x;
    if (n >= N) return;

    float x[EMB];
    const float4* xp = (const float4*)(X + (size_t)n * EMB);
    float4 x0 = xp[0], x1 = xp[1], x2 = xp[2], x3 = xp[3];
    x[0] = x0.x; x[1] = x0.y; x[2] = x0.z; x[3] = x0.w;
    x[4] = x1.x; x[5] = x1.y; x[6] = x1.z; x[7] = x1.w;
    x[8] = x2.x; x[9] = x2.y; x[10] = x2.z; x[11] = x2.w;
    x[12] = x3.x; x[13] = x3.y; x[14] = x3.z; x[15] = x3.w;

    float y[EMB];
#pragma unroll
    for (int j = 0; j < EMB; ++j) {
        float a = sb[j];
#pragma unroll
        for (int k = 0; k < EMB; ++k) a = fmaf(sW[j * EMB + k], x[k], a);
        y[j] = a;
    }

    float4* yp = (float4*)(Y + (size_t)n * EMB);
    yp[0] = make_float4(y[0], y[1], y[2], y[3]);
    yp[1] = make_float4(y[4], y[5], y[6], y[7]);
    yp[2] = make_float4(y[8], y[9], y[10], y[11]);
    yp[3] = make_float4(y[12], y[13], y[14], y[15]);
}

// ---------------------------------------------------------------------------
// Kernel 2: per-edge relu + scatter-add.
// 16 lanes per edge (one per channel). pre = TL[l] + TR[r] + ef*wedge
// (b_left is folded into TL). S[r] += relu(pre); cnt[r] += 1.
// ---------------------------------------------------------------------------
__global__ __launch_bounds__(256) void edge_scatter_kernel(
    const int* __restrict__ idx, const float* __restrict__ ef,
    const float* __restrict__ TL, const float* __restrict__ TR,
    const float* __restrict__ wedge, float* __restrict__ S,
    unsigned int* __restrict__ cnt, int E) {
    int gid = blockIdx.x * blockDim.x + threadIdx.x;
    int e = gid >> 4;
    int t = gid & 15;
    if (e >= E) return;

    int l = idx[e];
    int r = idx[E + e];
    float v = TL[(size_t)l * EMB + t] + TR[(size_t)r * EMB + t] + ef[e] * wedge[t];
    v = fmaxf(v, 0.0f);
    atomicAdd(S + (size_t)r * EMB + t, v);
    if (t == 0) atomicAdd(cnt + r, 1u);
}

// ---------------------------------------------------------------------------
// Kernel 3: per-right-node epilogue.
// agg = S[r] @ Wf.T + cnt*bf ; post = relu(agg) @ Wp.T + bp ;
// cat = [post, right[r]] ; h = relu(cat @ Wo1.T + bo1) ; out = h @ Wo2.T + bo2
// ---------------------------------------------------------------------------
__global__ __launch_bounds__(256) void epilogue_kernel(
    const float* __restrict__ S, const unsigned int* __restrict__ cnt,
    const float* __restrict__ right,
    const float* __restrict__ Wf, const float* __restrict__ bf,
    const float* __restrict__ Wp, const float* __restrict__ bp,
    const float* __restrict__ Wo1, const float* __restrict__ bo1,
    const float* __restrict__ Wo2, const float* __restrict__ bo2,
    float* __restrict__ out, int N) {
    __shared__ float sWf[256], sWp[256], sWo2[256], sWo1[512];
    __shared__ float sbf[16], sbp[16], sbo1[16], sbo2[16];
    for (int i = threadIdx.x; i < 256; i += blockDim.x) {
        sWf[i] = Wf[i]; sWp[i] = Wp[i]; sWo2[i] = Wo2[i];
    }
    for (int i = threadIdx.x; i < 512; i += blockDim.x) sWo1[i] = Wo1[i];
    if (threadIdx.x < 16) {
        sbf[threadIdx.x] = bf[threadIdx.x];
        sbp[threadIdx.x] = bp[threadIdx.x];
        sbo1[threadIdx.x] = bo1[threadIdx.x];
        sbo2[threadIdx.x] = bo2[threadIdx.x];
    }
    __syncthreads();

    int n = blockIdx.x * blockDim.x + threadIdx.x;
    if (n >= N) return;

    float s[EMB];
    {
        const float4* sp = (const float4*)(S + (size_t)n * EMB);
        float4 a0 = sp[0], a1 = sp[1], a2 = sp[2], a3 = sp[3];
        s[0] = a0.x; s[1] = a0.y; s[2] = a0.z; s[3] = a0.w;
        s[4] = a1.x; s[5] = a1.y; s[6] = a1.z; s[7] = a1.w;
        s[8] = a2.x; s[9] = a2.y; s[10] = a2.z; s[11] = a2.w;
        s[12] = a3.x; s[13] = a3.y; s[14] = a3.z; s[15] = a3.w;
    }
    float c = (float)cnt[n];

    // agg then relu
    float ra[EMB];
#pragma unroll
    for (int j = 0; j < EMB; ++j) {
        float a = c * sbf[j];
#pragma unroll
        for (int k = 0; k < EMB; ++k) a = fmaf(sWf[j * EMB + k], s[k], a);
        ra[j] = fmaxf(a, 0.0f);
    }

    // post
    float p[EMB];
#pragma unroll
    for (int j = 0; j < EMB; ++j) {
        float a = sbp[j];
#pragma unroll
        for (int k = 0; k < EMB; ++k) a = fmaf(sWp[j * EMB + k], ra[k], a);
        p[j] = a;
    }

    // right features
    float rf[EMB];
    {
        const float4* rp = (const float4*)(right + (size_t)n * EMB);
        float4 a0 = rp[0], a1 = rp[1], a2 = rp[2], a3 = rp[3];
        rf[0] = a0.x; rf[1] = a0.y; rf[2] = a0.z; rf[3] = a0.w;
        rf[4] = a1.x; rf[5] = a1.y; rf[6] = a1.z; rf[7] = a1.w;
        rf[8] = a2.x; rf[9] = a2.y; rf[10] = a2.z; rf[11] = a2.w;
        rf[12] = a3.x; rf[13] = a3.y; rf[14] = a3.z; rf[15] = a3.w;
    }

    // h = relu([post, rf] @ Wo1.T + bo1)
    float h[EMB];
#pragma unroll
    for (int j = 0; j < EMB; ++j) {
        float a = sbo1[j];
#pragma unroll
        for (int k = 0; k < EMB; ++k) a = fmaf(sWo1[j * 32 + k], p[k], a);
#pragma unroll
        for (int k = 0; k < EMB; ++k) a = fmaf(sWo1[j * 32 + 16 + k], rf[k], a);
        h[j] = fmaxf(a, 0.0f);
    }

    // out = h @ Wo2.T + bo2
    float o[EMB];
#pragma unroll
    for (int j = 0; j < EMB; ++j) {
        float a = sbo2[j];
#pragma unroll
        for (int k = 0; k < EMB; ++k) a = fmaf(sWo2[j * EMB + k], h[k], a);
        o[j] = a;
    }

    float4* op = (float4*)(out + (size_t)n * EMB);
    op[0] = make_float4(o[0], o[1], o[2], o[3]);
    op[1] = make_float4(o[4], o[5], o[6], o[7]);
    op[2] = make_float4(o[8], o[9], o[10], o[11]);
    op[3] = make_float4(o[12], o[13], o[14], o[15]);
}

// ---------------------------------------------------------------------------
extern "C" void kernel_launch(void* const* d_in, const int* in_sizes, int n_in,
                              void* d_out, int out_size, void* d_ws, size_t ws_size,
                              hipStream_t stream) {
    const float* left  = (const float*)d_in[0];
    const float* ef    = (const float*)d_in[1];
    const float* right = (const float*)d_in[2];
    const int*   eidx  = (const int*)d_in[3];
    const float* W_left  = (const float*)d_in[4];
    const float* b_left  = (const float*)d_in[5];
    const float* W_edge  = (const float*)d_in[6];
    const float* W_right = (const float*)d_in[7];
    const float* W_final = (const float*)d_in[8];
    const float* b_final = (const float*)d_in[9];
    const float* W_post  = (const float*)d_in[10];
    const float* b_post  = (const float*)d_in[11];
    const float* W_out1  = (const float*)d_in[12];
    const float* b_out1  = (const float*)d_in[13];
    const float* W_out2  = (const float*)d_in[14];
    const float* b_out2  = (const float*)d_in[15];

    const int NL = in_sizes[0] / EMB;
    const int NR = in_sizes[2] / EMB;
    const int E  = in_sizes[1];

    // Workspace layout
    char* ws = (char*)d_ws;
    float* TL = (float*)ws;                                   // NL*16 f32
    float* TR = (float*)(ws + (size_t)NL * EMB * 4);          // NR*16 f32
    float* S  = (float*)(ws + (size_t)(NL + NR) * EMB * 4);   // NR*16 f32
    unsigned int* cnt = (unsigned int*)(ws + (size_t)(NL + NR + NR) * EMB * 4); // NR u32

    // Zero scatter accumulators (ws is re-poisoned before every launch)
    hipMemsetAsync(S, 0, (size_t)NR * EMB * 4 + (size_t)NR * 4, stream);

    // Node transforms (b_left folded into TL)
    {
        int blocks = (NL + 255) / 256;
        node_transform_kernel<<<blocks, 256, 0, stream>>>(left, W_left, b_left, TL, NL);
    }
    {
        int blocks = (NR + 255) / 256;
        node_transform_kernel<<<blocks, 256, 0, stream>>>(right, W_right, nullptr, TR, NR);
    }

    // Edge scatter: 16 lanes/edge
    {
        long long threads = (long long)E * 16;
        int blocks = (int)((threads + 255) / 256);
        edge_scatter_kernel<<<blocks, 256, 0, stream>>>(eidx, ef, TL, TR, W_edge, S, cnt, E);
    }

    // Epilogue
    {
        int blocks = (NR + 255) / 256;
        epilogue_kernel<<<blocks, 256, 0, stream>>>(
            S, cnt, right, W_final, b_final, W_post, b_post,
            W_out1, b_out1, W_out2, b_out2, (float*)d_out, NR);
    }
}